// Round 5
// baseline (284.670 us; speedup 1.0000x reference)
//
#include <hip/hip_runtime.h>
#include <hip/hip_bf16.h>

// out[b,e] = m[c,e] + sum_d z[b,d] * L[c,e,d],  c = components[b]
// v5: de-risked v4. THREE launches, all from harness-proven components:
//  K1 build_map (proven v1-v3): atomic counting-bucket, 1 block.
//  K2 zgather   (proven v2-v3): gather+convert z -> bf16 zb[k][slot][d].
//  K3 gmm_gemm  (v4 tile, proven bounds): NT=32, M=160, BK=32 -> 640 blocks,
//     28KB LDS dbuf -> 5 blocks/CU (LDS-limited; 72-ish VGPR doesn't cap),
//     all blocks co-resident, L streamed exactly once, count-aware trim.

#define DDIM  2048
#define BSAMP 1024
#define KCOMP 10
#define MPAD  160                      // max n_k pad; Binom(1024,0.1)+6sigma
#define NT    32                       // block N tile
#define BK    32                       // d-elems per iteration
#define NITER (DDIM / BK)              // 64
#define ABYTES (MPAD * BK * 2)         // 10240  (bf16 A stage)
#define BBYTES (NT * BK * 4)           // 4096   (fp32 B stage)
#define STAGE_BYTES (ABYTES + BBYTES)  // 14336

typedef __attribute__((ext_vector_type(8))) short bf16x8;  // 8 bf16 = 4 VGPRs
typedef __attribute__((ext_vector_type(4))) float f32x4;

__device__ __forceinline__ void async16(void* lds, const void* g) {
    __builtin_amdgcn_global_load_lds(
        (const __attribute__((address_space(1))) void*)g,
        (__attribute__((address_space(3))) void*)lds, 16, 0, 0);
}

__device__ __forceinline__ short bfs(float x) {
    __hip_bfloat16 h = __float2bfloat16(x);   // RNE
    return *reinterpret_cast<short*>(&h);
}

// Kernel 1: counting-bucket the 1024 samples by component (proven v1-v3).
__global__ void build_map(const int* __restrict__ comp,
                          int* __restrict__ rowmap,
                          int* __restrict__ counts) {
    __shared__ int sc[KCOMP];
    const int t = threadIdx.x;
    if (t < KCOMP) sc[t] = 0;
    __syncthreads();
    const int c = comp[t];
    const int r = atomicAdd(&sc[c], 1);
    if (r < MPAD) rowmap[c * MPAD + r] = t;
    __syncthreads();
    if (t < KCOMP) counts[t] = sc[t];
}

// Kernel 2: zb[k*MPAD + slot][d] = bf16(z[rowmap[k][slot]][d]) (proven v2-v3).
// Pad slots read garbage rowmap (masked in-bounds, finite) - epilogue masks.
__global__ void zgather(const float* __restrict__ z,
                        const int* __restrict__ rowmap,
                        short* __restrict__ zb) {
    const int ks  = blockIdx.x;                 // k*MPAD + slot
    const int t   = threadIdx.x;                // 0..255, 8 elems each
    const int src = rowmap[ks] & (BSAMP - 1);
    const float* zr = z + (size_t)src * DDIM + t * 8;
    f32x4 x = *(const f32x4*)zr;
    f32x4 y = *(const f32x4*)(zr + 4);
    bf16x8 r;
#pragma unroll
    for (int i = 0; i < 4; ++i) { r[i] = bfs(x[i]); r[4 + i] = bfs(y[i]); }
    *(bf16x8*)(zb + (size_t)ks * DDIM + t * 8) = r;
}

// Kernel 3: grid = (2048/NT, KCOMP) = 640 blocks, block = 256 (4 waves).
// Block tile 160x32; wave tile 80x16 (mh = M-half, nh = N-half). acc[5].
// LDS A: 160 rows x 32 bf16 (64B row = 4 chunks), chunk h = (g + (r>>1)) & 3.
// LDS B: 32 rows x 32 fp32 (128B row = 8 chunks), chunk h = g ^ (r & 7).
// Staging writes LDS linearly (global_load_lds); swizzle applied by
// pre-swizzling the per-lane GLOBAL source column (both-sides rule, m231).
__global__ __launch_bounds__(256, 4)
void gmm_gemm(const short* __restrict__ zb,
              const float* __restrict__ mvec,
              const float* __restrict__ Lmat,
              const int* __restrict__ rowmap,
              const int* __restrict__ counts,
              float* __restrict__ out) {
    __shared__ __attribute__((aligned(16))) char smem[2 * STAGE_BYTES];
    const int t    = threadIdx.x;
    const int lane = t & 63;
    const int w    = t >> 6;
    const int mh   = w >> 1;          // wave M-half (80 rows)
    const int nh   = w & 1;           // wave N-half (16 cols)
    const int k    = blockIdx.y;
    const int n0   = blockIdx.x * NT;
    const float* Lk = Lmat + (size_t)k * DDIM * DDIM;
    const short* zk = zb + (size_t)k * MPAD * DDIM;
    const int cnt  = counts[k];

    // count-aware trim: this wave's rows are mh*80 + mt*16 + {0..15}
    int mtmax = (cnt - mh * 80 + 15) >> 4;
    mtmax = mtmax < 0 ? 0 : (mtmax > 5 ? 5 : mtmax);

    // A staging: 640 chunks (row = c>>2, h = c&3): j=0,1 all threads, j=2 t<128
    const int ar0 = t >> 2,         ac0 = (((t & 3) - (ar0 >> 1)) & 3) * 8;
    const int ar1 = 64 + (t >> 2),  ac1 = (((t & 3) - (ar1 >> 1)) & 3) * 8;
    const int ar2 = 128 + (t >> 2), ac2 = (((t & 3) - (ar2 >> 1)) & 3) * 8;
    // B staging: 256 chunks (row = t>>3, h = t&7)
    const int br = t >> 3,          bc = ((t & 7) ^ (br & 7)) * 4;
    const unsigned ub = (unsigned)(t & ~63) * 16;   // wave-uniform byte base

    auto stage = [&](int buf, int it) {
        char* lb = smem + buf * STAGE_BYTES;
        const int d0 = it * BK;
        async16(lb + ub,        zk + (size_t)ar0 * DDIM + d0 + ac0);
        async16(lb + 4096 + ub, zk + (size_t)ar1 * DDIM + d0 + ac1);
        if (t < 128)
            async16(lb + 8192 + ub, zk + (size_t)ar2 * DDIM + d0 + ac2);
        async16(lb + ABYTES + ub, Lk + (size_t)(n0 + br) * DDIM + d0 + bc);
    };

    f32x4 acc[5];
#pragma unroll
    for (int mt = 0; mt < 5; ++mt) acc[mt] = (f32x4){0.f, 0.f, 0.f, 0.f};

    stage(0, 0);
    __syncthreads();                 // drains vmcnt -> buf0 ready

    const int fr = lane & 15;        // frag row
    const int g  = lane >> 4;        // k-group (8 elems) of this lane
    const int rb = nh * 16 + fr;     // B row (block-relative e)
    const int h0 = ((2 * g)     ^ (rb & 7)) * 4;
    const int h1 = ((2 * g + 1) ^ (rb & 7)) * 4;

    for (int it = 0; it < NITER; ++it) {
        if (it + 1 < NITER) stage((it + 1) & 1, it + 1);
        const char* lb = smem + (it & 1) * STAGE_BYTES;
        const short* A = (const short*)lb;
        const float* B = (const float*)(lb + ABYTES);

        f32x4 x = *(const f32x4*)(B + rb * 32 + h0);
        f32x4 y = *(const f32x4*)(B + rb * 32 + h1);
        bf16x8 bb;
#pragma unroll
        for (int i = 0; i < 4; ++i) { bb[i] = bfs(x[i]); bb[4 + i] = bfs(y[i]); }

#pragma unroll
        for (int mt = 0; mt < 5; ++mt) {
            if (mt < mtmax) {        // wave-uniform guard, static acc index
                const int ra = mh * 80 + mt * 16 + fr;
                const int gs = ((g + (ra >> 1)) & 3) * 8;
                bf16x8 a = *(const bf16x8*)(A + ra * 32 + gs);
                acc[mt] = __builtin_amdgcn_mfma_f32_16x16x32_bf16(a, bb, acc[mt], 0, 0, 0);
            }
        }
        __syncthreads();             // cur buf consumed; prefetch drained
    }

    // epilogue: C/D layout col=lane&15, row=(lane>>4)*4+reg (m89-verified)
    const int rquad = g * 4;
    const int e  = n0 + nh * 16 + fr;
    const float mu = mvec[k * DDIM + e];
#pragma unroll
    for (int mt = 0; mt < 5; ++mt) {
        if (mt < mtmax) {
            const int sb = mh * 80 + mt * 16 + rquad;
#pragma unroll
            for (int r = 0; r < 4; ++r) {
                const int slot = sb + r;
                if (slot < cnt) {
                    const int b = rowmap[k * MPAD + slot];
                    out[(size_t)b * DDIM + e] = acc[mt][r] + mu;
                }
            }
        }
    }
}

extern "C" void kernel_launch(void* const* d_in, const int* in_sizes, int n_in,
                              void* d_out, int out_size, void* d_ws, size_t ws_size,
                              hipStream_t stream) {
    const float* z    = (const float*)d_in[0];
    const float* mvec = (const float*)d_in[1];
    const float* Lmat = (const float*)d_in[2];
    const int* comp   = (const int*)d_in[3];
    float* out        = (float*)d_out;

    int* rowmap = (int*)d_ws;                         // K*MPAD ints = 6400 B
    int* counts = rowmap + KCOMP * MPAD;              // K ints
    short* zb   = (short*)((char*)d_ws + 8192);       // 16B-aligned, 6.55 MB

    build_map<<<1, BSAMP, 0, stream>>>(comp, rowmap, counts);
    zgather<<<KCOMP * MPAD, 256, 0, stream>>>(z, rowmap, zb);
    gmm_gemm<<<dim3(DDIM / NT, KCOMP), 256, 0, stream>>>(zb, mvec, Lmat,
                                                         rowmap, counts, out);
}

// Round 6
// 269.495 us; speedup vs baseline: 1.0563x; 1.0563x over previous
//
#include <hip/hip_runtime.h>
#include <hip/hip_bf16.h>

// out[b,e] = m[c,e] + sum_d z[b,d] * L[c,e,d],  c = components[b]
// v6: fix the TA-fragmentation bottleneck found in v5 (3860 cyc/iter vs ~900
// latency floor; ~250 scattered transactions per block-iter from row-strided
// staging). zb is now PRE-TILED into the exact LDS staging image:
//   zb[k][it][10240B tile], tile = 80 macro-rows (slot pairs) x 128B,
//   chunk c (16B, c = (slot&1)*4 + g) stored at (c ^ (mr&7))*16.
// A-stage becomes wave-contiguous 1KB global_load_lds (1 transaction/instr)
// and the A fragment read is bank-conflict-free (8 lanes cover each 128B
// macro-row; XOR term folds to the lane constant fra^frh).
// K1 build_map + K3 sync structure (2-buffer syncthreads) unchanged (proven).

#define DDIM  2048
#define BSAMP 1024
#define KCOMP 10
#define MPAD  160                      // max n_k pad; Binom(1024,0.1)+6sigma
#define NT    32                       // block N tile
#define BK    32                       // d-elems per iteration
#define NITER (DDIM / BK)              // 64
#define TILEB (MPAD * BK * 2)          // 10240  A tile bytes per (k,it)
#define ABYTES TILEB
#define BBYTES (NT * BK * 4)           // 4096   (fp32 B stage)
#define STAGE_BYTES (ABYTES + BBYTES)  // 14336

typedef __attribute__((ext_vector_type(8))) short bf16x8;  // 8 bf16 = 4 VGPRs
typedef __attribute__((ext_vector_type(4))) float f32x4;

__device__ __forceinline__ void async16(void* lds, const void* g) {
    __builtin_amdgcn_global_load_lds(
        (const __attribute__((address_space(1))) void*)g,
        (__attribute__((address_space(3))) void*)lds, 16, 0, 0);
}

__device__ __forceinline__ short bfs(float x) {
    __hip_bfloat16 h = __float2bfloat16(x);   // RNE
    return *reinterpret_cast<short*>(&h);
}

// Kernel 1: counting-bucket the 1024 samples by component (proven v1-v5).
__global__ void build_map(const int* __restrict__ comp,
                          int* __restrict__ rowmap,
                          int* __restrict__ counts) {
    __shared__ int sc[KCOMP];
    const int t = threadIdx.x;
    if (t < KCOMP) sc[t] = 0;
    __syncthreads();
    const int c = comp[t];
    const int r = atomicAdd(&sc[c], 1);
    if (r < MPAD) rowmap[c * MPAD + r] = t;
    __syncthreads();
    if (t < KCOMP) counts[t] = sc[t];
}

// Kernel 2: grid (KCOMP, MPAD/2), block 256. Block (k, sp) converts slot pair
// {2sp, 2sp+1} into the tiled zb image. Thread t, pass p handles tile
// it = p*32 + (t>>3), chunk c = t&7: 8 fp32 of z row (2sp + (c>>2)) at
// d = it*32 + (c&3)*8 -> 16B bf16 written at tile + sp*128 + ((c^(sp&7))*16).
// Writes are 128B-contiguous per 8 lanes (XOR permutes within the macro-row).
// Pad slots read garbage rowmap (masked in-bounds, finite) - epilogue masks.
__global__ void zgather(const float* __restrict__ z,
                        const int* __restrict__ rowmap,
                        short* __restrict__ zb) {
    const int k  = blockIdx.x;
    const int sp = blockIdx.y;                  // slot pair / macro-row
    const int t  = threadIdx.x;
    const int c  = t & 7;                       // chunk within macro-row
    const int g  = c & 3;
    const int s0 = rowmap[k * MPAD + 2 * sp]     & (BSAMP - 1);
    const int s1 = rowmap[k * MPAD + 2 * sp + 1] & (BSAMP - 1);
    const int src = (c >> 2) ? s1 : s0;
    const int swz = (c ^ (sp & 7)) * 16;        // byte offset within 128B
    char* kbase = (char*)zb + (size_t)k * NITER * TILEB + sp * 128 + swz;
#pragma unroll
    for (int p = 0; p < 2; ++p) {
        const int it = p * 32 + (t >> 3);
        const float* zr = z + (size_t)src * DDIM + it * BK + g * 8;
        f32x4 x = *(const f32x4*)zr;
        f32x4 y = *(const f32x4*)(zr + 4);
        bf16x8 r;
#pragma unroll
        for (int i = 0; i < 4; ++i) { r[i] = bfs(x[i]); r[4 + i] = bfs(y[i]); }
        *(bf16x8*)(kbase + (size_t)it * TILEB) = r;
    }
}

// Kernel 3: grid = (2048/NT, KCOMP) = 640 blocks, block = 256 (4 waves).
// Block tile 160x32; wave tile 80x16 (mh = M-half, nh = N-half). acc[5].
// LDS A: linear copy of the pre-tiled zb image (stage = 2.5 contiguous
//   1KB wave loads). Frag read: mr = mh*40+mt*8+(fr>>1), chunk
//   ((fr&1)*4+g) ^ (mr&7); mr&7 = fr>>1 (40 and mt*8 are 0 mod 8), so the
//   XOR is lane-constant -> addr = lane_base + mt*1024.
// LDS B: 32 rows x 32 fp32 (128B row, 8 chunks), chunk h = g ^ (r&7),
//   swizzle applied by pre-swizzling the per-lane GLOBAL source column.
__global__ __launch_bounds__(256, 4)
void gmm_gemm(const short* __restrict__ zb,
              const float* __restrict__ mvec,
              const float* __restrict__ Lmat,
              const int* __restrict__ rowmap,
              const int* __restrict__ counts,
              float* __restrict__ out) {
    __shared__ __attribute__((aligned(16))) char smem[2 * STAGE_BYTES];
    const int t    = threadIdx.x;
    const int lane = t & 63;
    const int w    = t >> 6;
    const int mh   = w >> 1;          // wave M-half (80 rows)
    const int nh   = w & 1;           // wave N-half (16 cols)
    const int k    = blockIdx.y;
    const int n0   = blockIdx.x * NT;
    const float* Lk = Lmat + (size_t)k * DDIM * DDIM;
    const char* zt  = (const char*)zb + (size_t)k * NITER * TILEB;
    const int cnt  = counts[k];

    // count-aware trim: this wave's rows are mh*80 + mt*16 + {0..15}
    int mtmax = (cnt - mh * 80 + 15) >> 4;
    mtmax = mtmax < 0 ? 0 : (mtmax > 5 ? 5 : mtmax);

    // B staging: 256 chunks (row = t>>3, h = t&7), pre-swizzled source col
    const int br = t >> 3,          bc = ((t & 7) ^ (br & 7)) * 4;
    const unsigned ub = (unsigned)(t & ~63) * 16;   // wave-uniform byte base

    auto stage = [&](int buf, int it) {
        char* lb = smem + buf * STAGE_BYTES;
        const char* at = zt + (size_t)it * TILEB;
        async16(lb + ub,        at + t * 16);          // A chunks 0-255
        async16(lb + 4096 + ub, at + 4096 + t * 16);   // A chunks 256-511
        if (t < 128)
            async16(lb + 8192 + ub, at + 8192 + t * 16);  // A chunks 512-639
        async16(lb + ABYTES + ub,
                Lk + (size_t)(n0 + br) * DDIM + it * BK + bc);
    };

    f32x4 acc[5];
#pragma unroll
    for (int mt = 0; mt < 5; ++mt) acc[mt] = (f32x4){0.f, 0.f, 0.f, 0.f};

    stage(0, 0);
    __syncthreads();                 // drains vmcnt -> buf0 ready

    const int fr = lane & 15;        // frag row
    const int g  = lane >> 4;        // k-group (8 elems) of this lane
    const int rb = nh * 16 + fr;     // B row (block-relative e)
    const int h0 = ((2 * g)     ^ (rb & 7)) * 4;
    const int h1 = ((2 * g + 1) ^ (rb & 7)) * 4;
    // A frag lane constants: mr = mh*40 + mt*8 + frh; chunk = fra ^ frh
    const int frh = fr >> 1;
    const int fra = (fr & 1) * 4 + g;
    const int abase = (mh * 40 + frh) * 128 + ((fra ^ frh) * 16);

    for (int it = 0; it < NITER; ++it) {
        if (it + 1 < NITER) stage((it + 1) & 1, it + 1);
        const char* lb = smem + (it & 1) * STAGE_BYTES;
        const float* B = (const float*)(lb + ABYTES);

        f32x4 x = *(const f32x4*)(B + rb * 32 + h0);
        f32x4 y = *(const f32x4*)(B + rb * 32 + h1);
        bf16x8 bb;
#pragma unroll
        for (int i = 0; i < 4; ++i) { bb[i] = bfs(x[i]); bb[4 + i] = bfs(y[i]); }

#pragma unroll
        for (int mt = 0; mt < 5; ++mt) {
            if (mt < mtmax) {        // wave-uniform guard, static acc index
                bf16x8 a = *(const bf16x8*)(lb + abase + mt * 1024);
                acc[mt] = __builtin_amdgcn_mfma_f32_16x16x32_bf16(a, bb, acc[mt], 0, 0, 0);
            }
        }
        __syncthreads();             // cur buf consumed; prefetch drained
    }

    // epilogue: C/D layout col=lane&15, row=(lane>>4)*4+reg (m89-verified)
    const int rquad = g * 4;
    const int e  = n0 + nh * 16 + fr;
    const float mu = mvec[k * DDIM + e];
#pragma unroll
    for (int mt = 0; mt < 5; ++mt) {
        if (mt < mtmax) {
            const int sb = mh * 80 + mt * 16 + rquad;
#pragma unroll
            for (int r = 0; r < 4; ++r) {
                const int slot = sb + r;
                if (slot < cnt) {
                    const int b = rowmap[k * MPAD + slot];
                    out[(size_t)b * DDIM + e] = acc[mt][r] + mu;
                }
            }
        }
    }
}

extern "C" void kernel_launch(void* const* d_in, const int* in_sizes, int n_in,
                              void* d_out, int out_size, void* d_ws, size_t ws_size,
                              hipStream_t stream) {
    const float* z    = (const float*)d_in[0];
    const float* mvec = (const float*)d_in[1];
    const float* Lmat = (const float*)d_in[2];
    const int* comp   = (const int*)d_in[3];
    float* out        = (float*)d_out;

    int* rowmap = (int*)d_ws;                         // K*MPAD ints = 6400 B
    int* counts = rowmap + KCOMP * MPAD;              // K ints
    short* zb   = (short*)((char*)d_ws + 8192);       // 16B-aligned, 6.55 MB

    build_map<<<1, BSAMP, 0, stream>>>(comp, rowmap, counts);
    zgather<<<dim3(KCOMP, MPAD / 2), 256, 0, stream>>>(z, rowmap, zb);
    gmm_gemm<<<dim3(DDIM / NT, KCOMP), 256, 0, stream>>>(zb, mvec, Lmat,
                                                         rowmap, counts, out);
}